// Round 10
// baseline (386.613 us; speedup 1.0000x reference)
//
#include <hip/hip_runtime.h>
#include <hip/hip_cooperative_groups.h>

namespace cg = cooperative_groups;

// ---------------------------------------------------------------------------
// color_invariant_quadruplet: 3-hop label gather + 6-way equality embedding sum
//
// ONE cooperative kernel, 3 phases, 2 grid syncs (round 10):
//   P0: table build (blocks 0..15) || hop1 8 edges/thread  (one-shot)
//   P1: hop2 8 edges/thread                                 (one-shot)
//   P2: per-block fused combo+write, 2048 edges/block:
//         phase A: 8 edges/thread -> 16 outstanding zh gathers -> uint2 to LDS
//         __syncthreads
//         phase B: r8's proven write loop -- each wave owns a contiguous
//                  128 KB stream, 128 x {ds_read combo, ds_read table row,
//                  1 KB wave-store}; NO global loads -> no vmcnt waits.
//
// NOT the round-2 trap: r2 died on a dependent global-load->store chain in a
// grid-stride loop; here every phase is one-shot fixed work, and the write
// loop sources from LDS only (r8 measured this exact shape at 5.15 TB/s).
// Write path closed at ~100us/5.15 TB/s (r3/r7/r8). This round removes the
// remaining inter-dispatch serialization (2 gaps + 2 drain/ramp convoys).
// ---------------------------------------------------------------------------

#define N_FEAT 64
#define CWEPB  2048   // edges per write-block in P2 (512 KB out, 2 KB combo)

typedef float f4 __attribute__((ext_vector_type(4)));

__device__ __forceinline__ unsigned combo6(unsigned p, unsigned q) {
    // p = (za | zc<<8), q = (zb | zd<<8)
    unsigned za = p & 0xffu, zc = p >> 8;
    unsigned zb = q & 0xffu, zd = q >> 8;
    return (unsigned)(za == zc)
         | ((unsigned)(za == zb) << 1)
         | ((unsigned)(zc == zb) << 2)
         | ((unsigned)(za == zd) << 3)
         | ((unsigned)(zc == zd) << 4)
         | ((unsigned)(zb == zd) << 5);
}

__global__ __launch_bounds__(256, 4)
void fused_all_kernel(const int* __restrict__ z,
                      const int* __restrict__ src_g,
                      const int* __restrict__ dst_g,
                      const int* __restrict__ src_h,
                      const int* __restrict__ dst_h,
                      const int* __restrict__ src_i,
                      const int* __restrict__ dst_i,
                      const float* __restrict__ e1,
                      const float* __restrict__ e2,
                      const float* __restrict__ e3,
                      const float* __restrict__ e4,
                      const float* __restrict__ e5,
                      const float* __restrict__ e6,
                      float* __restrict__ table,
                      unsigned short* __restrict__ zg,
                      unsigned short* __restrict__ zh,
                      float* __restrict__ out,
                      int E_G, int E_H, int E_I) {
    cg::grid_group grid = cg::this_grid();
    __shared__ f4    tbl[64 * 16];          // 16 KB
    __shared__ uint2 cmbv[CWEPB / 8];       // 2 KB combo bytes
    const int tid  = threadIdx.x;
    const int gtid = blockIdx.x * 256 + tid;

    // ---- P0a: 64x64 table, reference left-to-right add order (bit-exact) ----
    if (blockIdx.x < 16) {
        int idx = blockIdx.x * 256 + tid;   // 0..4095
        int cmb = idx >> 6;
        int f   = idx & (N_FEAT - 1);
        float v = e1[((cmb >> 0) & 1) * N_FEAT + f];
        v      += e2[((cmb >> 1) & 1) * N_FEAT + f];
        v      += e3[((cmb >> 2) & 1) * N_FEAT + f];
        v      += e4[((cmb >> 3) & 1) * N_FEAT + f];
        v      += e5[((cmb >> 4) & 1) * N_FEAT + f];
        v      += e6[((cmb >> 5) & 1) * N_FEAT + f];
        table[idx] = v;
    }
    // ---- P0b: hop1, 8 g-edges/thread (16 random z-gathers in flight) ----
    {
        int n8 = E_G >> 3;
        if (gtid < n8) {
            const int4* s4 = (const int4*)src_g;
            const int4* d4 = (const int4*)dst_g;
            int4 sa = s4[2 * gtid], sb = s4[2 * gtid + 1];
            int4 da = d4[2 * gtid], db = d4[2 * gtid + 1];
            unsigned r0 = ((unsigned)z[sa.x] & 0xffu) | (((unsigned)z[da.x] & 0xffu) << 8)
                        | (((unsigned)z[sa.y] & 0xffu) << 16) | (((unsigned)z[da.y] & 0xffu) << 24);
            unsigned r1 = ((unsigned)z[sa.z] & 0xffu) | (((unsigned)z[da.z] & 0xffu) << 8)
                        | (((unsigned)z[sa.w] & 0xffu) << 16) | (((unsigned)z[da.w] & 0xffu) << 24);
            unsigned r2 = ((unsigned)z[sb.x] & 0xffu) | (((unsigned)z[db.x] & 0xffu) << 8)
                        | (((unsigned)z[sb.y] & 0xffu) << 16) | (((unsigned)z[db.y] & 0xffu) << 24);
            unsigned r3 = ((unsigned)z[sb.z] & 0xffu) | (((unsigned)z[db.z] & 0xffu) << 8)
                        | (((unsigned)z[sb.w] & 0xffu) << 16) | (((unsigned)z[db.w] & 0xffu) << 24);
            ((uint4*)zg)[gtid] = make_uint4(r0, r1, r2, r3);
        } else {
            int e = (n8 << 3) + (gtid - n8);       // tail edges, scalar
            if (e < E_G) {
                zg[e] = (unsigned short)(((unsigned)z[src_g[e]] & 0xffu)
                                       | (((unsigned)z[dst_g[e]] & 0xffu) << 8));
            }
        }
    }
    grid.sync();

    // ---- P1: hop2, 8 h-edges/thread. zh = z_src[src_h] | z_dst[dst_h]<<8 ----
    {
        int n8 = E_H >> 3;
        if (gtid < n8) {
            const int4* s4 = (const int4*)src_h;
            const int4* d4 = (const int4*)dst_h;
            int4 sa = s4[2 * gtid], sb = s4[2 * gtid + 1];
            int4 da = d4[2 * gtid], db = d4[2 * gtid + 1];
            unsigned a0 = zg[sa.x], b0 = zg[da.x];
            unsigned a1 = zg[sa.y], b1 = zg[da.y];
            unsigned a2 = zg[sa.z], b2 = zg[da.z];
            unsigned a3 = zg[sa.w], b3 = zg[da.w];
            unsigned a4 = zg[sb.x], b4 = zg[db.x];
            unsigned a5 = zg[sb.y], b5 = zg[db.y];
            unsigned a6 = zg[sb.z], b6 = zg[db.z];
            unsigned a7 = zg[sb.w], b7 = zg[db.w];
            unsigned r0 = (a0 & 0xffu) | (b0 & 0xff00u) | ((a1 & 0xffu) << 16) | ((b1 & 0xff00u) << 16);
            unsigned r1 = (a2 & 0xffu) | (b2 & 0xff00u) | ((a3 & 0xffu) << 16) | ((b3 & 0xff00u) << 16);
            unsigned r2 = (a4 & 0xffu) | (b4 & 0xff00u) | ((a5 & 0xffu) << 16) | ((b5 & 0xff00u) << 16);
            unsigned r3 = (a6 & 0xffu) | (b6 & 0xff00u) | ((a7 & 0xffu) << 16) | ((b7 & 0xff00u) << 16);
            ((uint4*)zh)[gtid] = make_uint4(r0, r1, r2, r3);
        } else {
            int e = (n8 << 3) + (gtid - n8);
            if (e < E_H) {
                unsigned a = zg[src_h[e]], b = zg[dst_h[e]];
                zh[e] = (unsigned short)((a & 0xffu) | (b & 0xff00u));
            }
        }
    }
    grid.sync();

    // ---- P2: fused combo + write, CWEPB edges per block ----
    const long long e0 = (long long)blockIdx.x * CWEPB;
    if (e0 >= E_I) return;                       // after last sync: safe
    int nb = E_I - (int)e0; if (nb > CWEPB) nb = CWEPB;

    // stage table (independent of combo path)
    const f4* t4 = (const f4*)table;
#pragma unroll
    for (int k = 0; k < 4; ++k)
        tbl[k * 256 + tid] = t4[k * 256 + tid];

    // phase A: 8 local edges per thread -> 16 outstanding zh gathers
    if (nb == CWEPB) {
        const int4* si = (const int4*)(src_i + e0);
        const int4* di = (const int4*)(dst_i + e0);
        int4 s0 = si[tid * 2], s1 = si[tid * 2 + 1];
        int4 d0 = di[tid * 2], d1 = di[tid * 2 + 1];
        unsigned r0 =  combo6(zh[s0.x], zh[d0.x])
                    | (combo6(zh[s0.y], zh[d0.y]) << 8)
                    | (combo6(zh[s0.z], zh[d0.z]) << 16)
                    | (combo6(zh[s0.w], zh[d0.w]) << 24);
        unsigned r1 =  combo6(zh[s1.x], zh[d1.x])
                    | (combo6(zh[s1.y], zh[d1.y]) << 8)
                    | (combo6(zh[s1.z], zh[d1.z]) << 16)
                    | (combo6(zh[s1.w], zh[d1.w]) << 24);
        cmbv[tid] = make_uint2(r0, r1);
    } else {
        unsigned r[2] = {0u, 0u};
        for (int j = 0; j < 8; ++j) {
            int le = tid * 8 + j;
            if (le < nb) {
                long long e = e0 + le;
                r[j >> 2] |= combo6(zh[src_i[e]], zh[dst_i[e]]) << ((j & 3) * 8);
            }
        }
        cmbv[tid] = make_uint2(r[0], r[1]);
    }
    __syncthreads();

    // phase B: wave w owns f4s [e0*16 + w*8192, +8192) -- contiguous 128 KB.
    const unsigned char* cmb = (const unsigned char*)cmbv;
    const int  w      = tid >> 6;
    const int  lane   = tid & 63;
    const int  c      = lane & 15;
    const int  leBase = w * (CWEPB / 4) + (lane >> 4);
    const long long fBase = e0 * 16 + (long long)w * (CWEPB * 16 / 4) + lane;
    constexpr int ITER = CWEPB * 16 / 4 / 64;            // 128

    if (nb == CWEPB) {
#pragma unroll 4
        for (int i = 0; i < ITER; ++i) {
            int le = leBase + i * 4;
            ((f4*)out)[fBase + (long long)i * 64] = tbl[(int)cmb[le] * 16 + c];
        }
    } else {
        const long long total = (long long)E_I * 16;
#pragma unroll 4
        for (int i = 0; i < ITER; ++i) {
            long long f = fBase + (long long)i * 64;
            if (f < total) {
                int le = leBase + i * 4;
                ((f4*)out)[f] = tbl[(int)cmb[le] * 16 + c];
            }
        }
    }
}

extern "C" void kernel_launch(void* const* d_in, const int* in_sizes, int n_in,
                              void* d_out, int out_size, void* d_ws, size_t ws_size,
                              hipStream_t stream) {
    const int* z     = (const int*)d_in[0];
    const int* src_g = (const int*)d_in[1];
    const int* dst_g = (const int*)d_in[2];
    const int* src_h = (const int*)d_in[3];
    const int* dst_h = (const int*)d_in[4];
    const int* src_i = (const int*)d_in[5];
    const int* dst_i = (const int*)d_in[6];
    const float* e1  = (const float*)d_in[7];
    const float* e2  = (const float*)d_in[8];
    const float* e3  = (const float*)d_in[9];
    const float* e4  = (const float*)d_in[10];
    const float* e5  = (const float*)d_in[11];
    const float* e6  = (const float*)d_in[12];

    int E_G = in_sizes[1];
    int E_H = in_sizes[3];
    int E_I = in_sizes[5];

    // Workspace: table | zg | zh (256B-aligned)
    char* ws = (char*)d_ws;
    float* table = (float*)ws;
    size_t off   = 64 * N_FEAT * sizeof(float);
    unsigned short* zg = (unsigned short*)(ws + off);
    off += (size_t)E_G * sizeof(unsigned short);
    off  = (off + 255) & ~(size_t)255;
    unsigned short* zh = (unsigned short*)(ws + off);

    float* out = (float*)d_out;

    // Grid: must cover P2 blocks, P0/P1 one-shot threads, and 16 table blocks.
    // For this problem: max(977, 489, 733, 16) = 977 blocks <= 4/CU x 256 CUs
    // co-residency (launch_bounds(256,4), 18.4 KB LDS) -> coop launch valid.
    int b3 = (E_I + CWEPB - 1) / CWEPB;
    int n8g = E_G >> 3, b1 = (n8g + (E_G - (n8g << 3)) + 255) / 256;
    int n8h = E_H >> 3, b2 = (n8h + (E_H - (n8h << 3)) + 255) / 256;
    int G = b3;
    if (b1 > G) G = b1;
    if (b2 > G) G = b2;
    if (G < 16) G = 16;

    void* args[] = {
        (void*)&z, (void*)&src_g, (void*)&dst_g,
        (void*)&src_h, (void*)&dst_h, (void*)&src_i, (void*)&dst_i,
        (void*)&e1, (void*)&e2, (void*)&e3, (void*)&e4, (void*)&e5, (void*)&e6,
        (void*)&table, (void*)&zg, (void*)&zh, (void*)&out,
        (void*)&E_G, (void*)&E_H, (void*)&E_I
    };
    hipLaunchCooperativeKernel((const void*)fused_all_kernel,
                               dim3(G), dim3(256), args, 0, stream);
}

// Round 11
// 145.924 us; speedup vs baseline: 2.6494x; 2.6494x over previous
//
#include <hip/hip_runtime.h>

// ---------------------------------------------------------------------------
// color_invariant_quadruplet: 3-hop label gather + 6-way equality embedding sum
//
// The 6 equality bits take 64 combinations; each maps to a fixed 64-float row.
// Pipeline (3 one-shot kernels -- NO cooperative launch: r2+r10 both showed
// grid.sync() kernels collapse to ~1-1.6 TB/s on streaming phases, likely
// from device-scope fence L2 writeback/invalidate across non-coherent XCDs):
//   K1 : hop1 packed labels (4 edges/thread, NT index loads) + table build
//   K2 : hop2 packed (z_ss, z_dd)            (4 edges/thread, NT index loads)
//   K3 : fused combo+write, WEPB=4096 edges/block:
//          phase A: 16 edges/thread, NT index loads, 32 outstanding zh
//                   gathers (zh reads NOT NT -- they want L2 residency)
//          barrier
//          phase B: proven write loop (r8/r9): each wave owns a contiguous
//                   256 KB stream, LDS-sourced, no vmcnt in the store stream.
//
// Round 11: revert r10's coop experiment to r9 (best, 142.0us) + two polish
// levers: (a) nontemporal loads on all one-touch index arrays so the 2MB zg /
// 3MB zh stay L2-resident under the 12/16 MB index streams; (b) hops back to
// 4 edges/thread (2x the blocks of r9's 8/thread -> better latency hiding).
// Write path closed at ~100us/5.15 TB/s (r3/r7/r8 three-shape pin).
// ---------------------------------------------------------------------------

#define N_FEAT 64
#define WEPB   4096   // edges per write-block (1 MB output, 4 KB combo slice)

typedef float f4 __attribute__((ext_vector_type(4)));
typedef int   i4 __attribute__((ext_vector_type(4)));

// K1: hop1, 4 g-edges/thread (8 independent random z-gathers in flight);
// blocks 0..15 also build the 64x64 table (reference left-to-right f32 add
// order -> bit-exact). Index arrays loaded nontemporal (one-touch).
__global__ void hop1_table_kernel(const int* __restrict__ z,
                                  const int* __restrict__ src_g,
                                  const int* __restrict__ dst_g,
                                  unsigned short* __restrict__ zg,
                                  const float* __restrict__ e1,
                                  const float* __restrict__ e2,
                                  const float* __restrict__ e3,
                                  const float* __restrict__ e4,
                                  const float* __restrict__ e5,
                                  const float* __restrict__ e6,
                                  float* __restrict__ table,
                                  int n) {
    int i  = blockIdx.x * blockDim.x + threadIdx.x;
    int n4 = n >> 2;
    if (i < n4) {
        i4 s = __builtin_nontemporal_load((const i4*)src_g + i);
        i4 d = __builtin_nontemporal_load((const i4*)dst_g + i);
        unsigned zs0 = (unsigned)z[s.x], zd0 = (unsigned)z[d.x];
        unsigned zs1 = (unsigned)z[s.y], zd1 = (unsigned)z[d.y];
        unsigned zs2 = (unsigned)z[s.z], zd2 = (unsigned)z[d.z];
        unsigned zs3 = (unsigned)z[s.w], zd3 = (unsigned)z[d.w];
        unsigned r0 = (zs0 & 0xffu) | ((zd0 & 0xffu) << 8)
                    | ((zs1 & 0xffu) << 16) | ((zd1 & 0xffu) << 24);
        unsigned r1 = (zs2 & 0xffu) | ((zd2 & 0xffu) << 8)
                    | ((zs3 & 0xffu) << 16) | ((zd3 & 0xffu) << 24);
        ((uint2*)zg)[i] = make_uint2(r0, r1);
    } else {
        int e = (n4 << 2) + (i - n4);      // tail edges, scalar
        if (e < n) {
            zg[e] = (unsigned short)(((unsigned)z[src_g[e]] & 0xffu)
                                   | (((unsigned)z[dst_g[e]] & 0xffu) << 8));
        }
    }
    if (blockIdx.x < 16) {
        int idx = blockIdx.x * 256 + threadIdx.x;   // 0..4095
        int cmb = idx >> 6;
        int f   = idx & (N_FEAT - 1);
        float v = e1[((cmb >> 0) & 1) * N_FEAT + f];
        v      += e2[((cmb >> 1) & 1) * N_FEAT + f];
        v      += e3[((cmb >> 2) & 1) * N_FEAT + f];
        v      += e4[((cmb >> 3) & 1) * N_FEAT + f];
        v      += e5[((cmb >> 4) & 1) * N_FEAT + f];
        v      += e6[((cmb >> 5) & 1) * N_FEAT + f];
        table[idx] = v;
    }
}

// K2: hop2, 4 h-edges/thread. zh = z_src[src_h] | z_dst[dst_h]<<8.
// 12 MB of h-indices loaded nontemporal so the 2 MB zg stays L2-resident.
__global__ void hop2_kernel(const unsigned short* __restrict__ zg,
                            const int* __restrict__ src_h,
                            const int* __restrict__ dst_h,
                            unsigned short* __restrict__ zh,
                            int n) {
    int i  = blockIdx.x * blockDim.x + threadIdx.x;
    int n4 = n >> 2;
    if (i < n4) {
        i4 s = __builtin_nontemporal_load((const i4*)src_h + i);
        i4 d = __builtin_nontemporal_load((const i4*)dst_h + i);
        unsigned a0 = zg[s.x], b0 = zg[d.x];
        unsigned a1 = zg[s.y], b1 = zg[d.y];
        unsigned a2 = zg[s.z], b2 = zg[d.z];
        unsigned a3 = zg[s.w], b3 = zg[d.w];
        unsigned r0 = (a0 & 0xffu) | (b0 & 0xff00u)
                    | ((a1 & 0xffu) << 16) | ((b1 & 0xff00u) << 16);
        unsigned r1 = (a2 & 0xffu) | (b2 & 0xff00u)
                    | ((a3 & 0xffu) << 16) | ((b3 & 0xff00u) << 16);
        ((uint2*)zh)[i] = make_uint2(r0, r1);
    } else {
        int e = (n4 << 2) + (i - n4);
        if (e < n) {
            unsigned a = zg[src_h[e]], b = zg[dst_h[e]];
            zh[e] = (unsigned short)((a & 0xffu) | (b & 0xff00u));
        }
    }
}

__device__ __forceinline__ unsigned combo6(unsigned p, unsigned q) {
    unsigned za = p & 0xffu, zc = p >> 8;
    unsigned zb = q & 0xffu, zd = q >> 8;
    return (unsigned)(za == zc)
         | ((unsigned)(za == zb) << 1)
         | ((unsigned)(zc == zb) << 2)
         | ((unsigned)(za == zd) << 3)
         | ((unsigned)(zc == zd) << 4)
         | ((unsigned)(zb == zd) << 5);
}

// K3: fused combo + fill-regime streaming write. WEPB=4096 edges (1 MB out)
// per block, ~489 blocks. Phase A: 16 local edges/thread (8 NT int4 index
// loads + 32 independent random zh gathers -> one uint4 ds_write); table
// (16 KB) staged in parallel. Phase B: wave w owns a contiguous 256 KB
// stream, 256 x {ds_read combo byte, ds_read_b128 table row, 1 KB store};
// no global loads -> stores never wait on vmcnt.
__global__ __launch_bounds__(256)
void fused_k3_kernel(const unsigned short* __restrict__ zh,
                     const int* __restrict__ src_i,
                     const int* __restrict__ dst_i,
                     const float* __restrict__ table,
                     float* __restrict__ out,
                     int nEdges) {
    __shared__ f4   tbl[64 * 16];          // 16 KB
    __shared__ uint4 cmbv[WEPB / 16];      // 4 KB of combo bytes
    const int tid = threadIdx.x;
    const long long e0 = (long long)blockIdx.x * WEPB;
    int nb = nEdges - (int)e0; if (nb > WEPB) nb = WEPB;

    // stage table (independent of combo path)
    const f4* t4 = (const f4*)table;
#pragma unroll
    for (int k = 0; k < 4; ++k)
        tbl[k * 256 + tid] = t4[k * 256 + tid];

    // phase A: 16 local edges per thread
    if (nb == WEPB) {
        const i4* si = (const i4*)(src_i + e0);
        const i4* di = (const i4*)(dst_i + e0);
        i4 s0 = __builtin_nontemporal_load(si + tid * 4 + 0);
        i4 s1 = __builtin_nontemporal_load(si + tid * 4 + 1);
        i4 s2 = __builtin_nontemporal_load(si + tid * 4 + 2);
        i4 s3 = __builtin_nontemporal_load(si + tid * 4 + 3);
        i4 d0 = __builtin_nontemporal_load(di + tid * 4 + 0);
        i4 d1 = __builtin_nontemporal_load(di + tid * 4 + 1);
        i4 d2 = __builtin_nontemporal_load(di + tid * 4 + 2);
        i4 d3 = __builtin_nontemporal_load(di + tid * 4 + 3);
        unsigned r0 =  combo6(zh[s0.x], zh[d0.x])
                    | (combo6(zh[s0.y], zh[d0.y]) << 8)
                    | (combo6(zh[s0.z], zh[d0.z]) << 16)
                    | (combo6(zh[s0.w], zh[d0.w]) << 24);
        unsigned r1 =  combo6(zh[s1.x], zh[d1.x])
                    | (combo6(zh[s1.y], zh[d1.y]) << 8)
                    | (combo6(zh[s1.z], zh[d1.z]) << 16)
                    | (combo6(zh[s1.w], zh[d1.w]) << 24);
        unsigned r2 =  combo6(zh[s2.x], zh[d2.x])
                    | (combo6(zh[s2.y], zh[d2.y]) << 8)
                    | (combo6(zh[s2.z], zh[d2.z]) << 16)
                    | (combo6(zh[s2.w], zh[d2.w]) << 24);
        unsigned r3 =  combo6(zh[s3.x], zh[d3.x])
                    | (combo6(zh[s3.y], zh[d3.y]) << 8)
                    | (combo6(zh[s3.z], zh[d3.z]) << 16)
                    | (combo6(zh[s3.w], zh[d3.w]) << 24);
        cmbv[tid] = make_uint4(r0, r1, r2, r3);
    } else {
        unsigned r[4] = {0u, 0u, 0u, 0u};
        for (int j = 0; j < 16; ++j) {
            int le = tid * 16 + j;
            if (le < nb) {
                long long e = e0 + le;
                unsigned c = combo6(zh[src_i[e]], zh[dst_i[e]]);
                r[j >> 2] |= c << ((j & 3) * 8);
            }
        }
        cmbv[tid] = make_uint4(r[0], r[1], r[2], r[3]);
    }
    __syncthreads();

    // phase B: wave w owns f4s [e0*16 + w*16384, +16384) -- contiguous 256 KB
    const unsigned char* cmb = (const unsigned char*)cmbv;
    const int  w      = tid >> 6;
    const int  lane   = tid & 63;
    const int  c      = lane & 15;
    const int  leBase = w * (WEPB / 4) + (lane >> 4);
    const long long fBase = e0 * 16 + (long long)w * (WEPB * 16 / 4) + lane;
    constexpr int ITER = WEPB * 16 / 4 / 64;            // 256

    if (nb == WEPB) {
#pragma unroll 4
        for (int i = 0; i < ITER; ++i) {
            int le = leBase + i * 4;
            ((f4*)out)[fBase + (long long)i * 64] = tbl[(int)cmb[le] * 16 + c];
        }
    } else {
        const long long total = (long long)nEdges * 16;
#pragma unroll 4
        for (int i = 0; i < ITER; ++i) {
            long long f = fBase + (long long)i * 64;
            if (f < total) {
                int le = leBase + i * 4;
                ((f4*)out)[f] = tbl[(int)cmb[le] * 16 + c];
            }
        }
    }
}

extern "C" void kernel_launch(void* const* d_in, const int* in_sizes, int n_in,
                              void* d_out, int out_size, void* d_ws, size_t ws_size,
                              hipStream_t stream) {
    const int* z     = (const int*)d_in[0];
    const int* src_g = (const int*)d_in[1];
    const int* dst_g = (const int*)d_in[2];
    const int* src_h = (const int*)d_in[3];
    const int* dst_h = (const int*)d_in[4];
    const int* src_i = (const int*)d_in[5];
    const int* dst_i = (const int*)d_in[6];
    const float* e1  = (const float*)d_in[7];
    const float* e2  = (const float*)d_in[8];
    const float* e3  = (const float*)d_in[9];
    const float* e4  = (const float*)d_in[10];
    const float* e5  = (const float*)d_in[11];
    const float* e6  = (const float*)d_in[12];

    int E_G = in_sizes[1];
    int E_H = in_sizes[3];
    int E_I = in_sizes[5];

    // Workspace: table | zg | zh (256B-aligned)
    char* ws = (char*)d_ws;
    float* table = (float*)ws;
    size_t off   = 64 * N_FEAT * sizeof(float);
    unsigned short* zg = (unsigned short*)(ws + off);
    off += (size_t)E_G * sizeof(unsigned short);
    off  = (off + 255) & ~(size_t)255;
    unsigned short* zh = (unsigned short*)(ws + off);

    float* out = (float*)d_out;

    // K1: hop1 (4 edges/thread) + table build
    {
        int n4 = E_G >> 2, nth = n4 + (E_G - (n4 << 2));
        int blocks = (nth + 255) / 256;
        if (blocks < 16) blocks = 16;
        hop1_table_kernel<<<blocks, 256, 0, stream>>>(z, src_g, dst_g, zg,
                                                      e1, e2, e3, e4, e5, e6,
                                                      table, E_G);
    }
    // K2: hop2 (4 edges/thread)
    {
        int n4 = E_H >> 2, nth = n4 + (E_H - (n4 << 2));
        hop2_kernel<<<(nth + 255) / 256, 256, 0, stream>>>(zg, src_h, dst_h, zh, E_H);
    }
    // K3: fused combo+write, 4096 edges per block
    {
        int blocks = (E_I + WEPB - 1) / WEPB;
        fused_k3_kernel<<<blocks, 256, 0, stream>>>(zh, src_i, dst_i, table, out, E_I);
    }
}

// Round 12
// 141.427 us; speedup vs baseline: 2.7337x; 1.0318x over previous
//
#include <hip/hip_runtime.h>

// ---------------------------------------------------------------------------
// color_invariant_quadruplet: 3-hop label gather + 6-way equality embedding sum
//
// FINAL (= round-9 config, best measured 141.97us; r11's NT-load + 4-edge-hop
// variant regressed to 145.9 -> reverted).
//
// The 6 equality bits take 64 combinations; each maps to a fixed 64-float row.
// Pipeline (3 one-shot kernels):
//   K1 : hop1 packed labels (8 edges/thread) + table build (blocks 0..15)
//   K2 : hop2 packed (z_ss, z_dd)            (8 edges/thread)
//   K3 : FUSED combo+write, WEPB=4096 edges/block (~489 blocks):
//          phase A: 16 edges/thread -> 32 outstanding zh gathers -> 16 combo
//                   bytes as one uint4 ds_write; table staged in parallel
//          barrier
//          phase B: each wave owns a contiguous 256KB store stream,
//                   256 x {ds_read combo, ds_read table row, 1KB wave-store};
//                   no global loads -> stores never wait on vmcnt.
//
// Session findings (measured):
//  - write pinned at ~5.15 TB/s across 3 shapes (r3/r7/r8) -> ~100us closed
//  - NT stores (r6) AND NT loads (r11) both regress on gfx950
//  - coop/grid.sync collapses streaming BW (r2: 1.0, r10: 1.6 TB/s)
//  - K3a->K3 fusion: -6.6us (r9); further hop tweaks neutral/negative
// ---------------------------------------------------------------------------

#define N_FEAT 64
#define WEPB   4096   // edges per write-block (1 MB output, 4 KB combo slice)

typedef float f4 __attribute__((ext_vector_type(4)));

// K1: hop1, 8 g-edges/thread (16 random z-gathers in flight); blocks 0..15
// also build the 64x64 table (reference left-to-right f32 order -> bit-exact).
__global__ void hop1_table_kernel(const int* __restrict__ z,
                                  const int* __restrict__ src_g,
                                  const int* __restrict__ dst_g,
                                  unsigned short* __restrict__ zg,
                                  const float* __restrict__ e1,
                                  const float* __restrict__ e2,
                                  const float* __restrict__ e3,
                                  const float* __restrict__ e4,
                                  const float* __restrict__ e5,
                                  const float* __restrict__ e6,
                                  float* __restrict__ table,
                                  int n) {
    int i  = blockIdx.x * blockDim.x + threadIdx.x;
    int n8 = n >> 3;
    if (i < n8) {
        const int4* s4 = (const int4*)src_g;
        const int4* d4 = (const int4*)dst_g;
        int4 sa = s4[2 * i], sb = s4[2 * i + 1];
        int4 da = d4[2 * i], db = d4[2 * i + 1];
        unsigned r0 = ((unsigned)z[sa.x] & 0xffu) | (((unsigned)z[da.x] & 0xffu) << 8)
                    | (((unsigned)z[sa.y] & 0xffu) << 16) | (((unsigned)z[da.y] & 0xffu) << 24);
        unsigned r1 = ((unsigned)z[sa.z] & 0xffu) | (((unsigned)z[da.z] & 0xffu) << 8)
                    | (((unsigned)z[sa.w] & 0xffu) << 16) | (((unsigned)z[da.w] & 0xffu) << 24);
        unsigned r2 = ((unsigned)z[sb.x] & 0xffu) | (((unsigned)z[db.x] & 0xffu) << 8)
                    | (((unsigned)z[sb.y] & 0xffu) << 16) | (((unsigned)z[db.y] & 0xffu) << 24);
        unsigned r3 = ((unsigned)z[sb.z] & 0xffu) | (((unsigned)z[db.z] & 0xffu) << 8)
                    | (((unsigned)z[sb.w] & 0xffu) << 16) | (((unsigned)z[db.w] & 0xffu) << 24);
        ((uint4*)zg)[i] = make_uint4(r0, r1, r2, r3);
    } else {
        int e = (n8 << 3) + (i - n8);      // tail edges, scalar
        if (e < n) {
            zg[e] = (unsigned short)(((unsigned)z[src_g[e]] & 0xffu)
                                   | (((unsigned)z[dst_g[e]] & 0xffu) << 8));
        }
    }
    if (blockIdx.x < 16) {
        int idx = blockIdx.x * 256 + threadIdx.x;   // 0..4095
        int cmb = idx >> 6;
        int f   = idx & (N_FEAT - 1);
        float v = e1[((cmb >> 0) & 1) * N_FEAT + f];
        v      += e2[((cmb >> 1) & 1) * N_FEAT + f];
        v      += e3[((cmb >> 2) & 1) * N_FEAT + f];
        v      += e4[((cmb >> 3) & 1) * N_FEAT + f];
        v      += e5[((cmb >> 4) & 1) * N_FEAT + f];
        v      += e6[((cmb >> 5) & 1) * N_FEAT + f];
        table[idx] = v;
    }
}

// K2: hop2, 8 h-edges/thread (16 random zg-gathers in flight).
// zh = z_src[src_h] | z_dst[dst_h]<<8.
__global__ void hop2_kernel(const unsigned short* __restrict__ zg,
                            const int* __restrict__ src_h,
                            const int* __restrict__ dst_h,
                            unsigned short* __restrict__ zh,
                            int n) {
    int i  = blockIdx.x * blockDim.x + threadIdx.x;
    int n8 = n >> 3;
    if (i < n8) {
        const int4* s4 = (const int4*)src_h;
        const int4* d4 = (const int4*)dst_h;
        int4 sa = s4[2 * i], sb = s4[2 * i + 1];
        int4 da = d4[2 * i], db = d4[2 * i + 1];
        unsigned a0 = zg[sa.x], b0 = zg[da.x];
        unsigned a1 = zg[sa.y], b1 = zg[da.y];
        unsigned a2 = zg[sa.z], b2 = zg[da.z];
        unsigned a3 = zg[sa.w], b3 = zg[da.w];
        unsigned a4 = zg[sb.x], b4 = zg[db.x];
        unsigned a5 = zg[sb.y], b5 = zg[db.y];
        unsigned a6 = zg[sb.z], b6 = zg[db.z];
        unsigned a7 = zg[sb.w], b7 = zg[db.w];
        unsigned r0 = (a0 & 0xffu) | (b0 & 0xff00u) | ((a1 & 0xffu) << 16) | ((b1 & 0xff00u) << 16);
        unsigned r1 = (a2 & 0xffu) | (b2 & 0xff00u) | ((a3 & 0xffu) << 16) | ((b3 & 0xff00u) << 16);
        unsigned r2 = (a4 & 0xffu) | (b4 & 0xff00u) | ((a5 & 0xffu) << 16) | ((b5 & 0xff00u) << 16);
        unsigned r3 = (a6 & 0xffu) | (b6 & 0xff00u) | ((a7 & 0xffu) << 16) | ((b7 & 0xff00u) << 16);
        ((uint4*)zh)[i] = make_uint4(r0, r1, r2, r3);
    } else {
        int e = (n8 << 3) + (i - n8);
        if (e < n) {
            unsigned a = zg[src_h[e]], b = zg[dst_h[e]];
            zh[e] = (unsigned short)((a & 0xffu) | (b & 0xff00u));
        }
    }
}

__device__ __forceinline__ unsigned combo6(unsigned p, unsigned q) {
    unsigned za = p & 0xffu, zc = p >> 8;
    unsigned zb = q & 0xffu, zd = q >> 8;
    return (unsigned)(za == zc)
         | ((unsigned)(za == zb) << 1)
         | ((unsigned)(zc == zb) << 2)
         | ((unsigned)(za == zd) << 3)
         | ((unsigned)(zc == zd) << 4)
         | ((unsigned)(zb == zd) << 5);
}

// K3: fused combo + fill-regime streaming write. WEPB=4096 edges (1 MB out)
// per block, ~489 blocks (all co-resident at ~2/CU).
// Phase A: thread t computes combo for local edges [16t,16t+16): 8 int4
//          index loads + 32 independent random zh gathers -> one uint4
//          ds_write. Table (16 KB) staged in parallel.
// Phase B: wave w owns a contiguous 256 KB stream,
//          256 x {ds_read combo byte, ds_read_b128 table row, 1KB store};
//          no global loads -> stores never wait on vmcnt.
__global__ __launch_bounds__(256)
void fused_k3_kernel(const unsigned short* __restrict__ zh,
                     const int* __restrict__ src_i,
                     const int* __restrict__ dst_i,
                     const float* __restrict__ table,
                     float* __restrict__ out,
                     int nEdges) {
    __shared__ f4   tbl[64 * 16];          // 16 KB
    __shared__ uint4 cmbv[WEPB / 16];      // 4 KB of combo bytes
    const int tid = threadIdx.x;
    const long long e0 = (long long)blockIdx.x * WEPB;
    int nb = nEdges - (int)e0; if (nb > WEPB) nb = WEPB;

    // stage table (independent of combo path)
    const f4* t4 = (const f4*)table;
#pragma unroll
    for (int k = 0; k < 4; ++k)
        tbl[k * 256 + tid] = t4[k * 256 + tid];

    // phase A: 16 local edges per thread
    if (nb == WEPB) {
        const int4* si = (const int4*)(src_i + e0);
        const int4* di = (const int4*)(dst_i + e0);
        int4 s0 = si[tid * 4 + 0], s1 = si[tid * 4 + 1],
             s2 = si[tid * 4 + 2], s3 = si[tid * 4 + 3];
        int4 d0 = di[tid * 4 + 0], d1 = di[tid * 4 + 1],
             d2 = di[tid * 4 + 2], d3 = di[tid * 4 + 3];
        unsigned r0 =  combo6(zh[s0.x], zh[d0.x])
                    | (combo6(zh[s0.y], zh[d0.y]) << 8)
                    | (combo6(zh[s0.z], zh[d0.z]) << 16)
                    | (combo6(zh[s0.w], zh[d0.w]) << 24);
        unsigned r1 =  combo6(zh[s1.x], zh[d1.x])
                    | (combo6(zh[s1.y], zh[d1.y]) << 8)
                    | (combo6(zh[s1.z], zh[d1.z]) << 16)
                    | (combo6(zh[s1.w], zh[d1.w]) << 24);
        unsigned r2 =  combo6(zh[s2.x], zh[d2.x])
                    | (combo6(zh[s2.y], zh[d2.y]) << 8)
                    | (combo6(zh[s2.z], zh[d2.z]) << 16)
                    | (combo6(zh[s2.w], zh[d2.w]) << 24);
        unsigned r3 =  combo6(zh[s3.x], zh[d3.x])
                    | (combo6(zh[s3.y], zh[d3.y]) << 8)
                    | (combo6(zh[s3.z], zh[d3.z]) << 16)
                    | (combo6(zh[s3.w], zh[d3.w]) << 24);
        cmbv[tid] = make_uint4(r0, r1, r2, r3);
    } else {
        unsigned r[4] = {0u, 0u, 0u, 0u};
        for (int j = 0; j < 16; ++j) {
            int le = tid * 16 + j;
            if (le < nb) {
                long long e = e0 + le;
                unsigned c = combo6(zh[src_i[e]], zh[dst_i[e]]);
                r[j >> 2] |= c << ((j & 3) * 8);
            }
        }
        cmbv[tid] = make_uint4(r[0], r[1], r[2], r[3]);
    }
    __syncthreads();

    // phase B: wave w owns f4s [e0*16 + w*16384, +16384) -- contiguous 256 KB
    const unsigned char* cmb = (const unsigned char*)cmbv;
    const int  w      = tid >> 6;
    const int  lane   = tid & 63;
    const int  c      = lane & 15;
    const int  leBase = w * (WEPB / 4) + (lane >> 4);
    const long long fBase = e0 * 16 + (long long)w * (WEPB * 16 / 4) + lane;
    constexpr int ITER = WEPB * 16 / 4 / 64;            // 256

    if (nb == WEPB) {
#pragma unroll 4
        for (int i = 0; i < ITER; ++i) {
            int le = leBase + i * 4;
            ((f4*)out)[fBase + (long long)i * 64] = tbl[(int)cmb[le] * 16 + c];
        }
    } else {
        const long long total = (long long)nEdges * 16;
#pragma unroll 4
        for (int i = 0; i < ITER; ++i) {
            long long f = fBase + (long long)i * 64;
            if (f < total) {
                int le = leBase + i * 4;
                ((f4*)out)[f] = tbl[(int)cmb[le] * 16 + c];
            }
        }
    }
}

extern "C" void kernel_launch(void* const* d_in, const int* in_sizes, int n_in,
                              void* d_out, int out_size, void* d_ws, size_t ws_size,
                              hipStream_t stream) {
    const int* z     = (const int*)d_in[0];
    const int* src_g = (const int*)d_in[1];
    const int* dst_g = (const int*)d_in[2];
    const int* src_h = (const int*)d_in[3];
    const int* dst_h = (const int*)d_in[4];
    const int* src_i = (const int*)d_in[5];
    const int* dst_i = (const int*)d_in[6];
    const float* e1  = (const float*)d_in[7];
    const float* e2  = (const float*)d_in[8];
    const float* e3  = (const float*)d_in[9];
    const float* e4  = (const float*)d_in[10];
    const float* e5  = (const float*)d_in[11];
    const float* e6  = (const float*)d_in[12];

    int E_G = in_sizes[1];
    int E_H = in_sizes[3];
    int E_I = in_sizes[5];

    // Workspace: table | zg | zh (256B-aligned)
    char* ws = (char*)d_ws;
    float* table = (float*)ws;
    size_t off   = 64 * N_FEAT * sizeof(float);
    unsigned short* zg = (unsigned short*)(ws + off);
    off += (size_t)E_G * sizeof(unsigned short);
    off  = (off + 255) & ~(size_t)255;
    unsigned short* zh = (unsigned short*)(ws + off);

    float* out = (float*)d_out;

    // K1: hop1 (8 edges/thread) + table build
    {
        int n8 = E_G >> 3, nth = n8 + (E_G - (n8 << 3));
        int blocks = (nth + 255) / 256;
        if (blocks < 16) blocks = 16;
        hop1_table_kernel<<<blocks, 256, 0, stream>>>(z, src_g, dst_g, zg,
                                                      e1, e2, e3, e4, e5, e6,
                                                      table, E_G);
    }
    // K2: hop2 (8 edges/thread)
    {
        int n8 = E_H >> 3, nth = n8 + (E_H - (n8 << 3));
        hop2_kernel<<<(nth + 255) / 256, 256, 0, stream>>>(zg, src_h, dst_h, zh, E_H);
    }
    // K3: fused combo+write, 4096 edges per block
    {
        int blocks = (E_I + WEPB - 1) / WEPB;
        fused_k3_kernel<<<blocks, 256, 0, stream>>>(zh, src_i, dst_i, table, out, E_I);
    }
}